// Round 8
// baseline (419.954 us; speedup 1.0000x reference)
//
#include <hip/hip_runtime.h>
#include <hip/hip_bf16.h>

static constexpr int NN = 50000;   // nodes
static constexpr int NE = 800000;  // edges
static constexpr int CH = 64;      // in/hidden channels

static constexpr int BKN   = 128;                      // nodes per bucket
static constexpr int NBKT  = (NN + BKN - 1) / BKN;     // 391
static constexpr int CAP   = 2560;                     // per-bucket cap (Poisson(2048) + 11 sigma)
static constexpr int CHUNK = 4096;                     // edges per k_bin block
static constexpr int NBIN  = (NE + CHUNK - 1) / CHUNK; // 196

// ---------------- x -> bf16 + one-time W1 transpose + bcur zero -------------
__global__ __launch_bounds__(256) void k_cvt(const float* __restrict__ x,
                                             __hip_bfloat16* __restrict__ xb,
                                             const float* __restrict__ W1l,
                                             const float* __restrict__ W1r,
                                             float* __restrict__ WlT,
                                             float* __restrict__ WrT,
                                             int* __restrict__ bcur) {
    int t = blockIdx.x * 256 + threadIdx.x;
    int base = t * 4;
    if (base < NN * CH) {
        float4 v = *(const float4*)(x + base);
        xb[base + 0] = __float2bfloat16(v.x);
        xb[base + 1] = __float2bfloat16(v.y);
        xb[base + 2] = __float2bfloat16(v.z);
        xb[base + 3] = __float2bfloat16(v.w);
    }
    if (blockIdx.x == 0) {
        for (int i = threadIdx.x; i < CH * CH; i += 256) {
            int c = i >> 6, o = i & 63;
            WlT[i] = W1l[o * CH + c];   // WlT[c][o]
            WrT[i] = W1r[o * CH + c];
        }
        for (int i = threadIdx.x; i < 512; i += 256) bcur[i] = 0;
    }
}

// ---------------- bucket binning: stage (src | dlocal<<16) by 128-node bkt --
__global__ __launch_bounds__(256) void k_bin(const int* __restrict__ src,
                                             const int* __restrict__ dst,
                                             int* __restrict__ bcur,
                                             unsigned int* __restrict__ bstage) {
    __shared__ int lcnt[NBKT];
    __shared__ int gb[NBKT];
    const int tid = threadIdx.x;
    const int e0 = blockIdx.x * CHUNK;
    for (int i = tid; i < NBKT; i += 256) lcnt[i] = 0;
    __syncthreads();
    for (int i = 0; i < CHUNK / 256; ++i) {          // pass A: count
        int e = e0 + i * 256 + tid;
        if (e < NE) atomicAdd(&lcnt[dst[e] >> 7], 1);
    }
    __syncthreads();
    for (int b = tid; b < NBKT; b += 256) {          // reserve spans
        gb[b] = atomicAdd(&bcur[b], lcnt[b]) + b * CAP;
        lcnt[b] = 0;
    }
    __syncthreads();
    for (int i = 0; i < CHUNK / 256; ++i) {          // pass B: place
        int e = e0 + i * 256 + tid;
        if (e < NE) {
            int d = dst[e];
            int b = d >> 7;
            int r = atomicAdd(&lcnt[b], 1);
            int pos = gb[b] + r;
            if (pos < (b + 1) * CAP)
                bstage[pos] = (unsigned)src[e] | ((unsigned)(d & (BKN - 1)) << 16);
        }
    }
}

// ---------------- layer-1 bucket aggregate: LDS acc, edge-parallel ----------
// Block per bucket (512 thr = 8 waves). Wave = one edge: 64 lanes gather the
// bf16 row (128B, 2 lines) and ds_add_f32 into acc[dlocal][lane] (bank=lane,
// 2 lanes/bank = free). No per-node serial chain; gather latency hidden by
// 8 waves x 4-deep unroll. Finalize: mean = acc/deg, deg -> global.
__global__ __launch_bounds__(512) void k_gagg(const unsigned int* __restrict__ bstage,
                                              const int* __restrict__ bcur,
                                              const __hip_bfloat16* __restrict__ xb,
                                              float* __restrict__ mean,
                                              int* __restrict__ deg) {
    __shared__ float accf[BKN * CH];   // 32 KB
    __shared__ int scnt[BKN];
    const int b    = blockIdx.x;
    const int tid  = threadIdx.x;
    const int w    = tid >> 6;         // wave 0..7
    const int lane = tid & 63;
    const int cnt  = min(bcur[b], CAP);
    const unsigned int* sw = bstage + (size_t)b * CAP;

    for (int i = tid; i < BKN * CH; i += 512) accf[i] = 0.0f;
    for (int i = tid; i < BKN; i += 512) scnt[i] = 0;
    __syncthreads();

    int i = w;
    for (; i + 32 <= cnt; i += 32) {   // 4 edges in flight per wave
        unsigned w0 = sw[i], w1 = sw[i + 8], w2 = sw[i + 16], w3 = sw[i + 24];
        float v0 = __bfloat162float(xb[(w0 & 0xFFFFu) * CH + lane]);
        float v1 = __bfloat162float(xb[(w1 & 0xFFFFu) * CH + lane]);
        float v2 = __bfloat162float(xb[(w2 & 0xFFFFu) * CH + lane]);
        float v3 = __bfloat162float(xb[(w3 & 0xFFFFu) * CH + lane]);
        atomicAdd(&accf[(w0 >> 16) * CH + lane], v0);
        atomicAdd(&accf[(w1 >> 16) * CH + lane], v1);
        atomicAdd(&accf[(w2 >> 16) * CH + lane], v2);
        atomicAdd(&accf[(w3 >> 16) * CH + lane], v3);
        if (lane == 0) {
            atomicAdd(&scnt[w0 >> 16], 1);
            atomicAdd(&scnt[w1 >> 16], 1);
            atomicAdd(&scnt[w2 >> 16], 1);
            atomicAdd(&scnt[w3 >> 16], 1);
        }
    }
    for (; i < cnt; i += 8) {
        unsigned wd = sw[i];
        float v = __bfloat162float(xb[(wd & 0xFFFFu) * CH + lane]);
        atomicAdd(&accf[(wd >> 16) * CH + lane], v);
        if (lane == 0) atomicAdd(&scnt[wd >> 16], 1);
    }
    __syncthreads();

    const int nbase = b * BKN;
    for (int j = w; j < BKN; j += 8) {
        int n = nbase + j;
        if (n < NN) {
            int c = scnt[j];
            float inv = c ? 1.0f / (float)c : 0.0f;
            mean[(size_t)n * CH + lane] = accf[j * CH + lane] * inv;
            if (lane == 0) deg[n] = c;
        }
    }
}

// ---------------- fused tiled GEMM: [32 nodes x 128k] @ [128k x 64] ---------
__global__ __launch_bounds__(256, 2) void k_fused(
        const float* __restrict__ x, const float* __restrict__ mean,
        const float* __restrict__ WlT, const float* __restrict__ WrT,
        const float* __restrict__ b1,
        const float* __restrict__ W2l, const float* __restrict__ W2r,
        const float* __restrict__ b2,
        float* __restrict__ hl2, float* __restrict__ out) {
    __shared__ float As[32][132];
    __shared__ float Ws[128][64];
    const int tid = threadIdx.x;
    const int n0 = blockIdx.x * 32;

    for (int idx = tid; idx < 1024; idx += 256) {
        int part = idx >> 9, rem = idx & 511, row = rem >> 4, q = rem & 15;
        int n = n0 + row;
        float4 v = make_float4(0.f, 0.f, 0.f, 0.f);
        if (n < NN) {
            const float* sp = part ? (x + (size_t)n * CH) : (mean + (size_t)n * CH);
            v = *(const float4*)(sp + q * 4);
        }
        *(float4*)&As[row][part * 64 + q * 4] = v;
    }
    for (int idx = tid; idx < 2048; idx += 256) {
        int r = idx >> 4, q = idx & 15;
        const float* wp = (r < 64) ? (WlT + r * CH) : (WrT + (r - 64) * CH);
        *(float4*)&Ws[r][q * 4] = *(const float4*)(wp + q * 4);
    }
    __syncthreads();

    const int nd0 = (tid >> 4) * 2;
    const int oc0 = (tid & 15) * 4;
    float acc[2][4] = {{0.f, 0.f, 0.f, 0.f}, {0.f, 0.f, 0.f, 0.f}};

    for (int kb = 0; kb < 32; ++kb) {
        float4 a0 = *(const float4*)&As[nd0][kb * 4];
        float4 a1 = *(const float4*)&As[nd0 + 1][kb * 4];
        float4 w0 = *(const float4*)&Ws[kb * 4 + 0][oc0];
        float4 w1 = *(const float4*)&Ws[kb * 4 + 1][oc0];
        float4 w2 = *(const float4*)&Ws[kb * 4 + 2][oc0];
        float4 w3 = *(const float4*)&Ws[kb * 4 + 3][oc0];
#pragma unroll
        for (int j = 0; j < 4; ++j) {
            const float u0 = ((const float*)&w0)[j];
            const float u1 = ((const float*)&w1)[j];
            const float u2 = ((const float*)&w2)[j];
            const float u3 = ((const float*)&w3)[j];
            acc[0][j] = fmaf(a0.x, u0, fmaf(a0.y, u1, fmaf(a0.z, u2, fmaf(a0.w, u3, acc[0][j]))));
            acc[1][j] = fmaf(a1.x, u0, fmaf(a1.y, u1, fmaf(a1.z, u2, fmaf(a1.w, u3, acc[1][j]))));
        }
    }

    float b1v[4], wl0[4], wl1[4], wr0[4], wr1[4];
#pragma unroll
    for (int j = 0; j < 4; ++j) {
        b1v[j] = b1[oc0 + j];
        wl0[j] = W2l[oc0 + j];  wl1[j] = W2l[64 + oc0 + j];
        wr0[j] = W2r[oc0 + j];  wr1[j] = W2r[64 + oc0 + j];
    }
    const float b20 = b2[0], b21 = b2[1];
#pragma unroll
    for (int nd = 0; nd < 2; ++nd) {
        float a0 = 0.f, a1 = 0.f, r0 = 0.f, r1 = 0.f;
#pragma unroll
        for (int j = 0; j < 4; ++j) {
            const float h = fmaxf(acc[nd][j] + b1v[j], 0.0f);  // relu; dropout=id
            a0 = fmaf(h, wl0[j], a0);
            a1 = fmaf(h, wl1[j], a1);
            r0 = fmaf(h, wr0[j], r0);
            r1 = fmaf(h, wr1[j], r1);
        }
#pragma unroll
        for (int off = 1; off < 16; off <<= 1) {
            a0 += __shfl_xor(a0, off);
            a1 += __shfl_xor(a1, off);
            r0 += __shfl_xor(r0, off);
            r1 += __shfl_xor(r1, off);
        }
        const int n = n0 + nd0 + nd;
        if ((tid & 15) == 0 && n < NN) {
            *(float2*)(hl2 + (size_t)n * 2) = make_float2(a0, a1);
            *(float2*)(out + (size_t)n * 2) = make_float2(b20 + r0, b21 + r1);
        }
    }
}

// ---------------- layer-2 bucket aggregate: LDS float2 acc, thread/edge -----
__global__ __launch_bounds__(256) void k_gagg2(const unsigned int* __restrict__ bstage,
                                               const int* __restrict__ bcur,
                                               const int* __restrict__ deg,
                                               const float2* __restrict__ hl2,
                                               float2* __restrict__ out) {
    __shared__ float ax[BKN];
    __shared__ float ay[BKN];
    const int b   = blockIdx.x;
    const int tid = threadIdx.x;
    const int cnt = min(bcur[b], CAP);
    const unsigned int* sw = bstage + (size_t)b * CAP;

    if (tid < BKN) { ax[tid] = 0.0f; ay[tid] = 0.0f; }
    __syncthreads();

    int i = tid;
    for (; i + 512 <= cnt; i += 512) {          // 2 in flight
        unsigned w0 = sw[i], w1 = sw[i + 256];
        float2 v0 = hl2[w0 & 0xFFFFu];
        float2 v1 = hl2[w1 & 0xFFFFu];
        atomicAdd(&ax[w0 >> 16], v0.x); atomicAdd(&ay[w0 >> 16], v0.y);
        atomicAdd(&ax[w1 >> 16], v1.x); atomicAdd(&ay[w1 >> 16], v1.y);
    }
    for (; i < cnt; i += 256) {
        unsigned wd = sw[i];
        float2 v = hl2[wd & 0xFFFFu];
        atomicAdd(&ax[wd >> 16], v.x); atomicAdd(&ay[wd >> 16], v.y);
    }
    __syncthreads();

    const int nbase = b * BKN;
    if (tid < BKN && nbase + tid < NN) {
        const int n = nbase + tid;
        const int c = deg[n];
        const float inv = c ? 1.0f / (float)c : 0.0f;
        float2 o = out[n];
        o.x += ax[tid] * inv;
        o.y += ay[tid] * inv;
        out[n] = o;
    }
}

extern "C" void kernel_launch(void* const* d_in, const int* in_sizes, int n_in,
                              void* d_out, int out_size, void* d_ws, size_t ws_size,
                              hipStream_t stream) {
    const float* x   = (const float*)d_in[0];
    const int*   ei  = (const int*)d_in[1];
    const float* W1l = (const float*)d_in[2];
    const float* W1r = (const float*)d_in[3];
    const float* b1  = (const float*)d_in[4];
    const float* W2l = (const float*)d_in[5];
    const float* W2r = (const float*)d_in[6];
    const float* b2  = (const float*)d_in[7];
    float* out = (float*)d_out;

    const int* src = ei;        // edge_index[0, :]
    const int* dst = ei + NE;   // edge_index[1, :]

    // workspace layout (~23.8 MiB)
    char* wsp = (char*)d_ws;
    int*          bcur   = (int*)wsp;                              // 512
    int*          deg    = bcur + 512;                             // 50048
    unsigned int* bstage = (unsigned int*)(deg + 50048);           // NBKT*CAP ~ 4 MB
    float*        mean   = (float*)(bstage + (size_t)NBKT * CAP);  // NN*CH
    float*        hl2    = mean + (size_t)NN * CH;                 // NN*2
    __hip_bfloat16* xbf  = (__hip_bfloat16*)(hl2 + (size_t)NN * 2);// NN*CH bf16
    float*        WlT    = (float*)(xbf + (size_t)NN * CH);        // 4096
    float*        WrT    = WlT + CH * CH;                          // 4096

    k_cvt  <<<(NN * CH / 4 + 255) / 256, 256, 0, stream>>>(x, xbf, W1l, W1r, WlT, WrT, bcur);
    k_bin  <<<NBIN, 256, 0, stream>>>(src, dst, bcur, bstage);
    k_gagg <<<NBKT, 512, 0, stream>>>(bstage, bcur, xbf, mean, deg);
    k_fused<<<(NN + 31) / 32, 256, 0, stream>>>(
        x, mean, WlT, WrT, b1, W2l, W2r, b2, hl2, out);
    k_gagg2<<<NBKT, 256, 0, stream>>>(bstage, bcur, deg, (const float2*)hl2, (float2*)out);
}

// Round 9
// 130.783 us; speedup vs baseline: 3.2111x; 3.2111x over previous
//
#include <hip/hip_runtime.h>
#include <hip/hip_bf16.h>

static constexpr int NN = 50000;   // nodes
static constexpr int NE = 800000;  // edges
static constexpr int CH = 64;      // in/hidden channels

static constexpr int BK    = 1024;                    // nodes per bucket
static constexpr int NBKT  = (NN + BK - 1) / BK;      // 49
static constexpr int CAP   = 18432;                   // per-bucket staging cap (mean 16327, ~16 sigma)
static constexpr int CHUNK = 4096;                    // edges per k_bin block
static constexpr int NBIN  = (NE + CHUNK - 1) / CHUNK;// 196

// ---------------- x -> bf16 copy + one-time W1 transpose + bcur zero --------
__global__ __launch_bounds__(256) void k_cvt(const float* __restrict__ x,
                                             __hip_bfloat16* __restrict__ xb,
                                             const float* __restrict__ W1l,
                                             const float* __restrict__ W1r,
                                             float* __restrict__ WlT,
                                             float* __restrict__ WrT,
                                             int* __restrict__ bcur) {
    int t = blockIdx.x * 256 + threadIdx.x;
    int base = t * 4;
    if (base < NN * CH) {
        float4 v = *(const float4*)(x + base);
        xb[base + 0] = __float2bfloat16(v.x);
        xb[base + 1] = __float2bfloat16(v.y);
        xb[base + 2] = __float2bfloat16(v.z);
        xb[base + 3] = __float2bfloat16(v.w);
    }
    if (blockIdx.x == 0) {
        for (int i = threadIdx.x; i < CH * CH; i += 256) {
            int c = i >> 6, o = i & 63;
            WlT[i] = W1l[o * CH + c];   // WlT[c][o]
            WrT[i] = W1r[o * CH + c];
        }
        if (threadIdx.x < 64) bcur[threadIdx.x] = 0;   // replaces hipMemsetAsync
    }
}

// ---------------- pass 1: bucket binning (block-local count + span reserve) -
// Packed word: low 16 bits = src id (<65536), bits 16.. = dst & (BK-1).
// Per (block,bucket) contiguous runs (~84 edges = 336B) -> compact write-back.
__global__ __launch_bounds__(256) void k_bin(const int* __restrict__ src,
                                             const int* __restrict__ dst,
                                             int* __restrict__ bcur,
                                             unsigned int* __restrict__ bstage) {
    __shared__ int lcnt[NBKT];
    __shared__ int gb[NBKT];
    const int tid = threadIdx.x;
    const int e0 = blockIdx.x * CHUNK;
    for (int i = tid; i < NBKT; i += 256) lcnt[i] = 0;
    __syncthreads();
    for (int i = 0; i < CHUNK / 256; ++i) {          // pass A: count
        int e = e0 + i * 256 + tid;
        if (e < NE) atomicAdd(&lcnt[dst[e] >> 10], 1);
    }
    __syncthreads();
    for (int b = tid; b < NBKT; b += 256) {          // reserve spans
        gb[b] = atomicAdd(&bcur[b], lcnt[b]) + b * CAP;
        lcnt[b] = 0;
    }
    __syncthreads();
    for (int i = 0; i < CHUNK / 256; ++i) {          // pass B: place
        int e = e0 + i * 256 + tid;
        if (e < NE) {
            int d = dst[e];
            int b = d >> 10;
            int r = atomicAdd(&lcnt[b], 1);
            int pos = gb[b] + r;
            if (pos < (b + 1) * CAP)
                bstage[pos] = (unsigned)src[e] | ((unsigned)(d & (BK - 1)) << 16);
        }
    }
}

// ---------------- bucket-base scan (49 sizes, one wave) ---------------------
__global__ __launch_bounds__(64) void k_bkt(const int* __restrict__ bcur,
                                            int* __restrict__ bktbase,
                                            int* __restrict__ rowptr) {
    int lane = threadIdx.x;
    int v = (lane < NBKT) ? bcur[lane] : 0;
    int s = v;
#pragma unroll
    for (int off = 1; off < 64; off <<= 1) {
        int t = __shfl_up(s, off);
        if (lane >= off) s += t;
    }
    if (lane < NBKT) bktbase[lane] = s - v;   // exclusive
    if (lane == 0) rowptr[NN] = NE;
}

// ---------------- pass 2: per-bucket counting sort -> col, rowptr -----------
__global__ __launch_bounds__(256) void k_sort(const unsigned int* __restrict__ bstage,
                                              const int* __restrict__ bcur,
                                              const int* __restrict__ bktbase,
                                              int* __restrict__ rowptr,
                                              int* __restrict__ col) {
    __shared__ int ncnt[BK];
    __shared__ int wsum[4];
    __shared__ int wbase[4];
    const int b   = blockIdx.x;
    const int tid = threadIdx.x;
    const int cnt = min(bcur[b], CAP);
    const unsigned int* sw = bstage + (size_t)b * CAP;
    const int nbase = b * BK;
    const int nn = min(BK, NN - nbase);

    for (int i = tid; i < BK; i += 256) ncnt[i] = 0;
    __syncthreads();
    for (int i = tid; i < cnt; i += 256) atomicAdd(&ncnt[sw[i] >> 16], 1);
    __syncthreads();

    // exclusive scan of ncnt[0..1024): 4 contiguous elems per thread
    const int i0 = tid * 4;
    const int c0 = ncnt[i0], c1 = ncnt[i0 + 1], c2 = ncnt[i0 + 2], c3 = ncnt[i0 + 3];
    const int tsum = c0 + c1 + c2 + c3;
    int s = tsum;
    const int lane = tid & 63, w = tid >> 6;
#pragma unroll
    for (int off = 1; off < 64; off <<= 1) {
        int t = __shfl_up(s, off);
        if (lane >= off) s += t;
    }
    if (lane == 63) wsum[w] = s;
    __syncthreads();
    if (tid == 0) {
        int c = 0;
#pragma unroll
        for (int k = 0; k < 4; ++k) { int t = wsum[k]; wbase[k] = c; c += t; }
    }
    __syncthreads();
    const int tb = wbase[w] + (s - tsum);
    const int e0 = tb, e1 = tb + c0, e2 = tb + c0 + c1, e3 = tb + c0 + c1 + c2;

    const int base = bktbase[b];
    if (i0 + 0 < nn) rowptr[nbase + i0 + 0] = base + e0;
    if (i0 + 1 < nn) rowptr[nbase + i0 + 1] = base + e1;
    if (i0 + 2 < nn) rowptr[nbase + i0 + 2] = base + e2;
    if (i0 + 3 < nn) rowptr[nbase + i0 + 3] = base + e3;

    // reuse ncnt as place cursors
    ncnt[i0] = e0; ncnt[i0 + 1] = e1; ncnt[i0 + 2] = e2; ncnt[i0 + 3] = e3;
    __syncthreads();
    for (int i = tid; i < cnt; i += 256) {
        unsigned wd = sw[i];
        int r = atomicAdd(&ncnt[wd >> 16], 1);
        col[base + r] = (int)(wd & 0xFFFFu);
    }
}

// ---------------- layer-1 CSR mean-aggregate over bf16 x --------------------
// wave per node, lane = channel; 8 gathers in flight, 2 independent accs
__global__ __launch_bounds__(256) void k_agg1(const int* __restrict__ rowptr,
                                              const int* __restrict__ col,
                                              const __hip_bfloat16* __restrict__ xb,
                                              float* __restrict__ mean) {
    const int node = blockIdx.x * 4 + (threadIdx.x >> 6);
    const int lane = threadIdx.x & 63;
    if (node >= NN) return;
    const int beg = rowptr[node], end = rowptr[node + 1];
    float accA = 0.0f, accB = 0.0f;
    int i = beg;
    for (; i + 8 <= end; i += 8) {
        int c0 = col[i + 0], c1 = col[i + 1], c2 = col[i + 2], c3 = col[i + 3];
        int c4 = col[i + 4], c5 = col[i + 5], c6 = col[i + 6], c7 = col[i + 7];
        float v0 = __bfloat162float(xb[c0 * CH + lane]);
        float v1 = __bfloat162float(xb[c1 * CH + lane]);
        float v2 = __bfloat162float(xb[c2 * CH + lane]);
        float v3 = __bfloat162float(xb[c3 * CH + lane]);
        float v4 = __bfloat162float(xb[c4 * CH + lane]);
        float v5 = __bfloat162float(xb[c5 * CH + lane]);
        float v6 = __bfloat162float(xb[c6 * CH + lane]);
        float v7 = __bfloat162float(xb[c7 * CH + lane]);
        accA += (v0 + v1) + (v2 + v3);
        accB += (v4 + v5) + (v6 + v7);
    }
    for (; i < end; ++i) accA += __bfloat162float(xb[col[i] * CH + lane]);
    const float inv = (end > beg) ? 1.0f / (float)(end - beg) : 0.0f;
    mean[(size_t)node * CH + lane] = (accA + accB) * inv;
}

// ---------------- fused tiled GEMM: [32 nodes x 128k] @ [128k x 64] ---------
// Canonical LDS-tiled f32 GEMM; per-thread acc[2][4] (8 VGPRs). Epilogue
// fuses bias+relu and the 64->2 layer-2 projections via 16-lane butterflies.
__global__ __launch_bounds__(256, 2) void k_fused(
        const float* __restrict__ x, const float* __restrict__ mean,
        const float* __restrict__ WlT, const float* __restrict__ WrT,
        const float* __restrict__ b1,
        const float* __restrict__ W2l, const float* __restrict__ W2r,
        const float* __restrict__ b2,
        float* __restrict__ hl2, float* __restrict__ out) {
    __shared__ float As[32][132];
    __shared__ float Ws[128][64];
    const int tid = threadIdx.x;
    const int n0 = blockIdx.x * 32;

    for (int idx = tid; idx < 1024; idx += 256) {
        int part = idx >> 9, rem = idx & 511, row = rem >> 4, q = rem & 15;
        int n = n0 + row;
        float4 v = make_float4(0.f, 0.f, 0.f, 0.f);
        if (n < NN) {
            const float* sp = part ? (x + (size_t)n * CH) : (mean + (size_t)n * CH);
            v = *(const float4*)(sp + q * 4);
        }
        *(float4*)&As[row][part * 64 + q * 4] = v;
    }
    for (int idx = tid; idx < 2048; idx += 256) {
        int r = idx >> 4, q = idx & 15;
        const float* wp = (r < 64) ? (WlT + r * CH) : (WrT + (r - 64) * CH);
        *(float4*)&Ws[r][q * 4] = *(const float4*)(wp + q * 4);
    }
    __syncthreads();

    const int nd0 = (tid >> 4) * 2;   // 0..30
    const int oc0 = (tid & 15) * 4;   // 0..60
    float acc[2][4] = {{0.f, 0.f, 0.f, 0.f}, {0.f, 0.f, 0.f, 0.f}};

    for (int kb = 0; kb < 32; ++kb) {
        float4 a0 = *(const float4*)&As[nd0][kb * 4];
        float4 a1 = *(const float4*)&As[nd0 + 1][kb * 4];
        float4 w0 = *(const float4*)&Ws[kb * 4 + 0][oc0];
        float4 w1 = *(const float4*)&Ws[kb * 4 + 1][oc0];
        float4 w2 = *(const float4*)&Ws[kb * 4 + 2][oc0];
        float4 w3 = *(const float4*)&Ws[kb * 4 + 3][oc0];
#pragma unroll
        for (int j = 0; j < 4; ++j) {
            const float u0 = ((const float*)&w0)[j];
            const float u1 = ((const float*)&w1)[j];
            const float u2 = ((const float*)&w2)[j];
            const float u3 = ((const float*)&w3)[j];
            acc[0][j] = fmaf(a0.x, u0, fmaf(a0.y, u1, fmaf(a0.z, u2, fmaf(a0.w, u3, acc[0][j]))));
            acc[1][j] = fmaf(a1.x, u0, fmaf(a1.y, u1, fmaf(a1.z, u2, fmaf(a1.w, u3, acc[1][j]))));
        }
    }

    float b1v[4], wl0[4], wl1[4], wr0[4], wr1[4];
#pragma unroll
    for (int j = 0; j < 4; ++j) {
        b1v[j] = b1[oc0 + j];
        wl0[j] = W2l[oc0 + j];  wl1[j] = W2l[64 + oc0 + j];
        wr0[j] = W2r[oc0 + j];  wr1[j] = W2r[64 + oc0 + j];
    }
    const float b20 = b2[0], b21 = b2[1];
#pragma unroll
    for (int nd = 0; nd < 2; ++nd) {
        float a0 = 0.f, a1 = 0.f, r0 = 0.f, r1 = 0.f;
#pragma unroll
        for (int j = 0; j < 4; ++j) {
            const float h = fmaxf(acc[nd][j] + b1v[j], 0.0f);  // relu; dropout=id
            a0 = fmaf(h, wl0[j], a0);
            a1 = fmaf(h, wl1[j], a1);
            r0 = fmaf(h, wr0[j], r0);
            r1 = fmaf(h, wr1[j], r1);
        }
#pragma unroll
        for (int off = 1; off < 16; off <<= 1) {
            a0 += __shfl_xor(a0, off);
            a1 += __shfl_xor(a1, off);
            r0 += __shfl_xor(r0, off);
            r1 += __shfl_xor(r1, off);
        }
        const int n = n0 + nd0 + nd;
        if ((tid & 15) == 0 && n < NN) {
            *(float2*)(hl2 + (size_t)n * 2) = make_float2(a0, a1);
            *(float2*)(out + (size_t)n * 2) = make_float2(b20 + r0, b21 + r1);
        }
    }
}

// ---------------- layer-2 CSR mean-aggregate + add into out -----------------
__global__ __launch_bounds__(256) void k_agg2(const int* __restrict__ rowptr,
                                              const int* __restrict__ col,
                                              const float2* __restrict__ hl2,
                                              float2* __restrict__ out) {
    int t = blockIdx.x * 256 + threadIdx.x;
    int node = t >> 3;
    int sl = t & 7;
    if (node >= NN) return;
    const int beg = rowptr[node], end = rowptr[node + 1];
    float ax = 0.0f, ay = 0.0f;
    for (int i = beg + sl; i < end; i += 8) {
        float2 v = hl2[col[i]];
        ax += v.x; ay += v.y;
    }
#pragma unroll
    for (int off = 4; off > 0; off >>= 1) {
        ax += __shfl_xor(ax, off);
        ay += __shfl_xor(ay, off);
    }
    if (sl == 0) {
        const float inv = (end > beg) ? 1.0f / (float)(end - beg) : 0.0f;
        float2 o = out[node];
        o.x += ax * inv;
        o.y += ay * inv;
        out[node] = o;
    }
}

extern "C" void kernel_launch(void* const* d_in, const int* in_sizes, int n_in,
                              void* d_out, int out_size, void* d_ws, size_t ws_size,
                              hipStream_t stream) {
    const float* x   = (const float*)d_in[0];
    const int*   ei  = (const int*)d_in[1];
    const float* W1l = (const float*)d_in[2];
    const float* W1r = (const float*)d_in[3];
    const float* b1  = (const float*)d_in[4];
    const float* W2l = (const float*)d_in[5];
    const float* W2r = (const float*)d_in[6];
    const float* b2  = (const float*)d_in[7];
    float* out = (float*)d_out;

    const int* src = ei;        // edge_index[0, :]
    const int* dst = ei + NE;   // edge_index[1, :]

    // workspace layout (~25.4 MiB)
    char* wsp = (char*)d_ws;
    int*          bcur    = (int*)wsp;                             // 64
    int*          bktbase = bcur + 64;                             // 64
    int*          rowptr  = bktbase + 64;                          // NN+1 (pad 50052)
    unsigned int* bstage  = (unsigned int*)(rowptr + 50052);       // NBKT*CAP
    int*          col     = (int*)(bstage + (size_t)NBKT * CAP);   // NE
    float*        mean    = (float*)(col + NE);                    // NN*CH
    float*        hl2     = mean + (size_t)NN * CH;                // NN*2
    __hip_bfloat16* xbf   = (__hip_bfloat16*)(hl2 + (size_t)NN * 2); // NN*CH bf16
    float*        WlT     = (float*)(xbf + (size_t)NN * CH);       // 4096
    float*        WrT     = WlT + CH * CH;                         // 4096

    k_cvt <<<(NN * CH / 4 + 255) / 256, 256, 0, stream>>>(x, xbf, W1l, W1r, WlT, WrT, bcur);
    k_bin <<<NBIN, 256, 0, stream>>>(src, dst, bcur, bstage);
    k_bkt <<<1, 64, 0, stream>>>(bcur, bktbase, rowptr);
    k_sort<<<NBKT, 256, 0, stream>>>(bstage, bcur, bktbase, rowptr, col);
    k_agg1<<<(NN + 3) / 4, 256, 0, stream>>>(rowptr, col, xbf, mean);
    k_fused<<<(NN + 31) / 32, 256, 0, stream>>>(
        x, mean, WlT, WrT, b1, W2l, W2r, b2, hl2, out);
    k_agg2<<<(8 * NN + 255) / 256, 256, 0, stream>>>(
        rowptr, col, (const float2*)hl2, (float2*)out);
}

// Round 10
// 93.734 us; speedup vs baseline: 4.4803x; 1.3952x over previous
//
#include <hip/hip_runtime.h>
#include <hip/hip_bf16.h>

static constexpr int NN = 50000;   // nodes
static constexpr int NE = 800000;  // edges
static constexpr int CH = 64;      // in/hidden channels

static constexpr int BK    = 256;                     // nodes per bucket
static constexpr int NBKT  = (NN + BK - 1) / BK;      // 196
static constexpr int CAP   = 4608;                    // cap: mean 4096 + 8 sigma
static constexpr int CHUNK = 4096;                    // edges per k_bin block
static constexpr int NBIN  = (NE + CHUNK - 1) / CHUNK;// 196

// ---------------- x -> bf16 copy + one-time W1 transpose + bcur zero --------
__global__ __launch_bounds__(256) void k_cvt(const float* __restrict__ x,
                                             __hip_bfloat16* __restrict__ xb,
                                             const float* __restrict__ W1l,
                                             const float* __restrict__ W1r,
                                             float* __restrict__ WlT,
                                             float* __restrict__ WrT,
                                             int* __restrict__ bcur) {
    int t = blockIdx.x * 256 + threadIdx.x;
    int base = t * 4;
    if (base < NN * CH) {
        float4 v = *(const float4*)(x + base);
        xb[base + 0] = __float2bfloat16(v.x);
        xb[base + 1] = __float2bfloat16(v.y);
        xb[base + 2] = __float2bfloat16(v.z);
        xb[base + 3] = __float2bfloat16(v.w);
    }
    if (blockIdx.x == 0) {
        for (int i = threadIdx.x; i < CH * CH; i += 256) {
            int c = i >> 6, o = i & 63;
            WlT[i] = W1l[o * CH + c];   // WlT[c][o]
            WrT[i] = W1r[o * CH + c];
        }
        bcur[threadIdx.x] = 0;          // 256 >= NBKT; replaces hipMemsetAsync
    }
}

// ---------------- pass 1: bucket binning (dst cached in regs between passes)
// Packed word: low 16 bits = src id (<65536), bits 16..23 = dst & 255.
__global__ __launch_bounds__(256) void k_bin(const int* __restrict__ src,
                                             const int* __restrict__ dst,
                                             int* __restrict__ bcur,
                                             unsigned int* __restrict__ bstage) {
    __shared__ int lcnt[NBKT];
    __shared__ int gb[NBKT];
    const int tid = threadIdx.x;
    const int e0 = blockIdx.x * CHUNK;
    int dloc[16];
    if (tid < NBKT) lcnt[tid] = 0;
    __syncthreads();
#pragma unroll
    for (int i = 0; i < 16; ++i) {                   // pass A: count
        int e = e0 + i * 256 + tid;
        int d = (e < NE) ? dst[e] : -1;
        dloc[i] = d;
        if (d >= 0) atomicAdd(&lcnt[d >> 8], 1);
    }
    __syncthreads();
    if (tid < NBKT) {                                // reserve spans
        gb[tid] = atomicAdd(&bcur[tid], lcnt[tid]) + tid * CAP;
        lcnt[tid] = 0;
    }
    __syncthreads();
#pragma unroll
    for (int i = 0; i < 16; ++i) {                   // pass B: place
        int d = dloc[i];
        if (d >= 0) {
            int e = e0 + i * 256 + tid;
            int b = d >> 8;
            int r = atomicAdd(&lcnt[b], 1);
            int pos = gb[b] + r;
            if (pos < (b + 1) * CAP)
                bstage[pos] = (unsigned)src[e] | ((unsigned)(d & (BK - 1)) << 16);
        }
    }
}

// ---------------- pass 2: per-bucket counting sort (+inline bucket base) ----
// 196 blocks (full CU coverage). Each block computes its global base by
// summing bcur[0..b) (196 ints, trivial), then counting-sorts its <=CAP
// staged edges by exact node -> col, rowptr.
__global__ __launch_bounds__(256) void k_sort(const unsigned int* __restrict__ bstage,
                                              const int* __restrict__ bcur,
                                              int* __restrict__ rowptr,
                                              int* __restrict__ col) {
    __shared__ int ncnt[BK];
    __shared__ int w4[4];
    __shared__ int wsum[4];
    const int b   = blockIdx.x;
    const int tid = threadIdx.x;
    const int lane = tid & 63, w = tid >> 6;
    const int cnt = min(bcur[b], CAP);
    const unsigned int* sw = bstage + (size_t)b * CAP;

    // bucket base = exclusive prefix over bcur[0..b)
    int part = 0;
    for (int i = tid; i < b; i += 256) part += bcur[i];
#pragma unroll
    for (int off = 32; off > 0; off >>= 1) part += __shfl_xor(part, off);
    if (lane == 0) w4[w] = part;
    ncnt[tid] = 0;
    __syncthreads();
    const int base = w4[0] + w4[1] + w4[2] + w4[3];

    for (int i = tid; i < cnt; i += 256) atomicAdd(&ncnt[sw[i] >> 16], 1);
    __syncthreads();

    // exclusive scan of ncnt[256], one counter per thread
    const int v = ncnt[tid];
    int s = v;
#pragma unroll
    for (int off = 1; off < 64; off <<= 1) {
        int t = __shfl_up(s, off);
        if (lane >= off) s += t;
    }
    if (lane == 63) wsum[w] = s;
    __syncthreads();
    if (tid == 0) {
        int c = 0;
#pragma unroll
        for (int k = 0; k < 4; ++k) { int t = wsum[k]; wsum[k] = c; c += t; }
    }
    __syncthreads();
    const int excl = wsum[w] + s - v;

    const int n = b * BK + tid;
    if (n < NN) rowptr[n] = base + excl;
    if (b == NBKT - 1 && tid == 0) rowptr[NN] = NE;

    ncnt[tid] = excl;   // reuse as place cursor
    __syncthreads();
    for (int i = tid; i < cnt; i += 256) {
        unsigned wd = sw[i];
        int r = atomicAdd(&ncnt[wd >> 16], 1);
        col[base + r] = (int)(wd & 0xFFFFu);
    }
}

// ---------------- layer-1 CSR mean-aggregate over bf16 x --------------------
// wave per node; 16 lanes x ushort4 per edge -> 4 edges per instruction,
// unroll 2 (8 edges in flight). Cross-group shfl reduce; float4 store.
__global__ __launch_bounds__(256) void k_agg1(const int* __restrict__ rowptr,
                                              const int* __restrict__ col,
                                              const unsigned short* __restrict__ xbu,
                                              float* __restrict__ mean) {
    const int node = blockIdx.x * 4 + (threadIdx.x >> 6);
    const int lane = threadIdx.x & 63;
    const int g = lane >> 4;        // edge group 0..3
    const int s = lane & 15;        // channels s*4 .. s*4+3
    if (node >= NN) return;
    const int beg = rowptr[node], end = rowptr[node + 1];
    float a0 = 0.f, a1 = 0.f, a2 = 0.f, a3 = 0.f;
    int i = beg;
    for (; i + 8 <= end; i += 8) {
        const int eA = col[i + g];
        const int eB = col[i + 4 + g];
        ushort4 ua = *(const ushort4*)(xbu + eA * CH + s * 4);
        ushort4 ub = *(const ushort4*)(xbu + eB * CH + s * 4);
        a0 += __uint_as_float((unsigned)ua.x << 16) + __uint_as_float((unsigned)ub.x << 16);
        a1 += __uint_as_float((unsigned)ua.y << 16) + __uint_as_float((unsigned)ub.y << 16);
        a2 += __uint_as_float((unsigned)ua.z << 16) + __uint_as_float((unsigned)ub.z << 16);
        a3 += __uint_as_float((unsigned)ua.w << 16) + __uint_as_float((unsigned)ub.w << 16);
    }
    for (; i < end; i += 4) {
        if (g < end - i) {
            const int e = col[i + g];
            ushort4 u = *(const ushort4*)(xbu + e * CH + s * 4);
            a0 += __uint_as_float((unsigned)u.x << 16);
            a1 += __uint_as_float((unsigned)u.y << 16);
            a2 += __uint_as_float((unsigned)u.z << 16);
            a3 += __uint_as_float((unsigned)u.w << 16);
        }
    }
    a0 += __shfl_xor(a0, 16); a0 += __shfl_xor(a0, 32);
    a1 += __shfl_xor(a1, 16); a1 += __shfl_xor(a1, 32);
    a2 += __shfl_xor(a2, 16); a2 += __shfl_xor(a2, 32);
    a3 += __shfl_xor(a3, 16); a3 += __shfl_xor(a3, 32);
    if (lane < 16) {
        const float inv = (end > beg) ? 1.0f / (float)(end - beg) : 0.0f;
        *(float4*)(mean + (size_t)node * CH + lane * 4) =
            make_float4(a0 * inv, a1 * inv, a2 * inv, a3 * inv);
    }
}

// ---------------- fused tiled GEMM: [32 nodes x 128k] @ [128k x 64] ---------
__global__ __launch_bounds__(256, 2) void k_fused(
        const float* __restrict__ x, const float* __restrict__ mean,
        const float* __restrict__ WlT, const float* __restrict__ WrT,
        const float* __restrict__ b1,
        const float* __restrict__ W2l, const float* __restrict__ W2r,
        const float* __restrict__ b2,
        float* __restrict__ hl2, float* __restrict__ out) {
    __shared__ float As[32][132];
    __shared__ float Ws[128][64];
    const int tid = threadIdx.x;
    const int n0 = blockIdx.x * 32;

    for (int idx = tid; idx < 1024; idx += 256) {
        int part = idx >> 9, rem = idx & 511, row = rem >> 4, q = rem & 15;
        int n = n0 + row;
        float4 v = make_float4(0.f, 0.f, 0.f, 0.f);
        if (n < NN) {
            const float* sp = part ? (x + (size_t)n * CH) : (mean + (size_t)n * CH);
            v = *(const float4*)(sp + q * 4);
        }
        *(float4*)&As[row][part * 64 + q * 4] = v;
    }
    for (int idx = tid; idx < 2048; idx += 256) {
        int r = idx >> 4, q = idx & 15;
        const float* wp = (r < 64) ? (WlT + r * CH) : (WrT + (r - 64) * CH);
        *(float4*)&Ws[r][q * 4] = *(const float4*)(wp + q * 4);
    }
    __syncthreads();

    const int nd0 = (tid >> 4) * 2;   // 0..30
    const int oc0 = (tid & 15) * 4;   // 0..60
    float acc[2][4] = {{0.f, 0.f, 0.f, 0.f}, {0.f, 0.f, 0.f, 0.f}};

    for (int kb = 0; kb < 32; ++kb) {
        float4 a0 = *(const float4*)&As[nd0][kb * 4];
        float4 a1 = *(const float4*)&As[nd0 + 1][kb * 4];
        float4 w0 = *(const float4*)&Ws[kb * 4 + 0][oc0];
        float4 w1 = *(const float4*)&Ws[kb * 4 + 1][oc0];
        float4 w2 = *(const float4*)&Ws[kb * 4 + 2][oc0];
        float4 w3 = *(const float4*)&Ws[kb * 4 + 3][oc0];
#pragma unroll
        for (int j = 0; j < 4; ++j) {
            const float u0 = ((const float*)&w0)[j];
            const float u1 = ((const float*)&w1)[j];
            const float u2 = ((const float*)&w2)[j];
            const float u3 = ((const float*)&w3)[j];
            acc[0][j] = fmaf(a0.x, u0, fmaf(a0.y, u1, fmaf(a0.z, u2, fmaf(a0.w, u3, acc[0][j]))));
            acc[1][j] = fmaf(a1.x, u0, fmaf(a1.y, u1, fmaf(a1.z, u2, fmaf(a1.w, u3, acc[1][j]))));
        }
    }

    float b1v[4], wl0[4], wl1[4], wr0[4], wr1[4];
#pragma unroll
    for (int j = 0; j < 4; ++j) {
        b1v[j] = b1[oc0 + j];
        wl0[j] = W2l[oc0 + j];  wl1[j] = W2l[64 + oc0 + j];
        wr0[j] = W2r[oc0 + j];  wr1[j] = W2r[64 + oc0 + j];
    }
    const float b20 = b2[0], b21 = b2[1];
#pragma unroll
    for (int nd = 0; nd < 2; ++nd) {
        float a0 = 0.f, a1 = 0.f, r0 = 0.f, r1 = 0.f;
#pragma unroll
        for (int j = 0; j < 4; ++j) {
            const float h = fmaxf(acc[nd][j] + b1v[j], 0.0f);  // relu; dropout=id
            a0 = fmaf(h, wl0[j], a0);
            a1 = fmaf(h, wl1[j], a1);
            r0 = fmaf(h, wr0[j], r0);
            r1 = fmaf(h, wr1[j], r1);
        }
#pragma unroll
        for (int off = 1; off < 16; off <<= 1) {
            a0 += __shfl_xor(a0, off);
            a1 += __shfl_xor(a1, off);
            r0 += __shfl_xor(r0, off);
            r1 += __shfl_xor(r1, off);
        }
        const int n = n0 + nd0 + nd;
        if ((tid & 15) == 0 && n < NN) {
            *(float2*)(hl2 + (size_t)n * 2) = make_float2(a0, a1);
            *(float2*)(out + (size_t)n * 2) = make_float2(b20 + r0, b21 + r1);
        }
    }
}

// ---------------- layer-2 CSR mean-aggregate + add into out -----------------
__global__ __launch_bounds__(256) void k_agg2(const int* __restrict__ rowptr,
                                              const int* __restrict__ col,
                                              const float2* __restrict__ hl2,
                                              float2* __restrict__ out) {
    int t = blockIdx.x * 256 + threadIdx.x;
    int node = t >> 3;
    int sl = t & 7;
    if (node >= NN) return;
    const int beg = rowptr[node], end = rowptr[node + 1];
    float ax = 0.0f, ay = 0.0f;
    for (int i = beg + sl; i < end; i += 8) {
        float2 v = hl2[col[i]];
        ax += v.x; ay += v.y;
    }
#pragma unroll
    for (int off = 4; off > 0; off >>= 1) {
        ax += __shfl_xor(ax, off);
        ay += __shfl_xor(ay, off);
    }
    if (sl == 0) {
        const float inv = (end > beg) ? 1.0f / (float)(end - beg) : 0.0f;
        float2 o = out[node];
        o.x += ax * inv;
        o.y += ay * inv;
        out[node] = o;
    }
}

extern "C" void kernel_launch(void* const* d_in, const int* in_sizes, int n_in,
                              void* d_out, int out_size, void* d_ws, size_t ws_size,
                              hipStream_t stream) {
    const float* x   = (const float*)d_in[0];
    const int*   ei  = (const int*)d_in[1];
    const float* W1l = (const float*)d_in[2];
    const float* W1r = (const float*)d_in[3];
    const float* b1  = (const float*)d_in[4];
    const float* W2l = (const float*)d_in[5];
    const float* W2r = (const float*)d_in[6];
    const float* b2  = (const float*)d_in[7];
    float* out = (float*)d_out;

    const int* src = ei;        // edge_index[0, :]
    const int* dst = ei + NE;   // edge_index[1, :]

    // workspace layout (~27 MiB)
    char* wsp = (char*)d_ws;
    int*          bcur    = (int*)wsp;                             // 256
    int*          rowptr  = bcur + 256;                            // NN+1 (pad 50052)
    unsigned int* bstage  = (unsigned int*)(rowptr + 50052);       // NBKT*CAP ~3.6MB
    int*          col     = (int*)(bstage + (size_t)NBKT * CAP);   // NE
    float*        mean    = (float*)(col + NE);                    // NN*CH
    float*        hl2     = mean + (size_t)NN * CH;                // NN*2
    __hip_bfloat16* xbf   = (__hip_bfloat16*)(hl2 + (size_t)NN * 2); // NN*CH bf16
    float*        WlT     = (float*)(xbf + (size_t)NN * CH);       // 4096
    float*        WrT     = WlT + CH * CH;                         // 4096

    k_cvt <<<(NN * CH / 4 + 255) / 256, 256, 0, stream>>>(x, xbf, W1l, W1r, WlT, WrT, bcur);
    k_bin <<<NBIN, 256, 0, stream>>>(src, dst, bcur, bstage);
    k_sort<<<NBKT, 256, 0, stream>>>(bstage, bcur, rowptr, col);
    k_agg1<<<(NN + 3) / 4, 256, 0, stream>>>(rowptr, col, (const unsigned short*)xbf, mean);
    k_fused<<<(NN + 31) / 32, 256, 0, stream>>>(
        x, mean, WlT, WrT, b1, W2l, W2r, b2, hl2, out);
    k_agg2<<<(8 * NN + 255) / 256, 256, 0, stream>>>(
        rowptr, col, (const float2*)hl2, (float2*)out);
}

// Round 11
// 82.643 us; speedup vs baseline: 5.0816x; 1.1342x over previous
//
#include <hip/hip_runtime.h>
#include <hip/hip_bf16.h>

static constexpr int NN = 50000;   // nodes
static constexpr int NE = 800000;  // edges
static constexpr int CH = 64;      // in/hidden channels

static constexpr int BKN    = 256;                     // nodes per bucket
static constexpr int NBKT   = (NN + BKN - 1) / BKN;    // 196
static constexpr int CHUNK  = 4096;                    // edges per bin block
static constexpr int NBIN   = (NE + CHUNK - 1) / CHUNK;// 196
static constexpr int SUBCAP = 64;                      // per (bucket,binblk) cell cap (~mean 21, +9 sigma)
static constexpr int COLCAP = 4608;                    // per-bucket col span (~mean 4096, +8 sigma)
static constexpr int NCVT   = (NN * CH / 8 + 255) / 256; // 1563 cvt blocks

// ---------------- fused prep: x->bf16 + W1 transpose  ||  one-pass binning --
__global__ __launch_bounds__(256) void k_prep(
        const float* __restrict__ x, __hip_bfloat16* __restrict__ xb,
        const float* __restrict__ W1l, const float* __restrict__ W1r,
        float* __restrict__ WlT, float* __restrict__ WrT,
        const int* __restrict__ src, const int* __restrict__ dst,
        int* __restrict__ lcnt, unsigned int* __restrict__ bstage) {
    const int tid = threadIdx.x;
    if (blockIdx.x < NCVT) {
        // ---- cvt part: 8 bf16 per thread, uint4 store ----
        const int base = (blockIdx.x * 256 + tid) * 8;
        if (base < NN * CH) {
            float4 v0 = *(const float4*)(x + base);
            float4 v1 = *(const float4*)(x + base + 4);
            union { unsigned short us[8]; uint4 u4; } o;
            __hip_bfloat16 h;
            h = __float2bfloat16(v0.x); o.us[0] = *(unsigned short*)&h;
            h = __float2bfloat16(v0.y); o.us[1] = *(unsigned short*)&h;
            h = __float2bfloat16(v0.z); o.us[2] = *(unsigned short*)&h;
            h = __float2bfloat16(v0.w); o.us[3] = *(unsigned short*)&h;
            h = __float2bfloat16(v1.x); o.us[4] = *(unsigned short*)&h;
            h = __float2bfloat16(v1.y); o.us[5] = *(unsigned short*)&h;
            h = __float2bfloat16(v1.z); o.us[6] = *(unsigned short*)&h;
            h = __float2bfloat16(v1.w); o.us[7] = *(unsigned short*)&h;
            *(uint4*)(xb + base) = o.u4;
        }
        if (blockIdx.x == 0) {
            for (int i = tid; i < CH * CH; i += 256) {
                int c = i >> 6, o = i & 63;
                WlT[i] = W1l[o * CH + c];   // WlT[c][o]
                WrT[i] = W1r[o * CH + c];
            }
        }
    } else {
        // ---- bin part: one pass, fixed per-(bucket,block) cells ----
        const int blk = blockIdx.x - NCVT;
        __shared__ int cnt[NBKT];
        if (tid < NBKT) cnt[tid] = 0;
        __syncthreads();
        const int e0 = blk * CHUNK;
#pragma unroll
        for (int i = 0; i < 16; ++i) {
            int e = e0 + i * 256 + tid;
            if (e < NE) {
                int d = dst[e];
                int b = d >> 8;
                int r = atomicAdd(&cnt[b], 1);
                if (r < SUBCAP)
                    bstage[((size_t)b * NBIN + blk) * SUBCAP + r] =
                        (unsigned)src[e] | ((unsigned)(d & (BKN - 1)) << 16);
            }
        }
        __syncthreads();
        if (tid < NBKT) lcnt[blk * NBKT + tid] = min(cnt[tid], SUBCAP);
    }
}

// ---------------- per-bucket counting sort from cells -> col, beg, deg ------
__global__ __launch_bounds__(256) void k_sort(
        const unsigned int* __restrict__ bstage, const int* __restrict__ lcnt,
        int* __restrict__ begv, int* __restrict__ degv, int* __restrict__ col) {
    __shared__ int ccnt[256];
    __shared__ int ncnt[BKN];
    __shared__ int wsum[4];
    const int b   = blockIdx.x;
    const int tid = threadIdx.x;
    const int lane = tid & 63, w = tid >> 6;

    ccnt[tid] = (tid < NBIN) ? lcnt[tid * NBKT + b] : 0;
    ncnt[tid] = 0;
    __syncthreads();

    // count per node (cell per thread; independent loads, fire-forget atomics)
    if (tid < NBIN) {
        const unsigned int* cp = bstage + ((size_t)b * NBIN + tid) * SUBCAP;
        const int c = ccnt[tid];
        int j = 0;
        for (; j + 4 <= c; j += 4) {
            unsigned w0 = cp[j], w1 = cp[j + 1], w2 = cp[j + 2], w3 = cp[j + 3];
            atomicAdd(&ncnt[w0 >> 16], 1);
            atomicAdd(&ncnt[w1 >> 16], 1);
            atomicAdd(&ncnt[w2 >> 16], 1);
            atomicAdd(&ncnt[w3 >> 16], 1);
        }
        for (; j < c; ++j) atomicAdd(&ncnt[cp[j] >> 16], 1);
    }
    __syncthreads();

    // exclusive scan of ncnt[256] -> per-node offset; emit beg/deg
    const int v = ncnt[tid];
    int s = v;
#pragma unroll
    for (int off = 1; off < 64; off <<= 1) {
        int t = __shfl_up(s, off);
        if (lane >= off) s += t;
    }
    if (lane == 63) wsum[w] = s;
    __syncthreads();
    if (tid == 0) {
        int c = 0;
#pragma unroll
        for (int k = 0; k < 4; ++k) { int t = wsum[k]; wsum[k] = c; c += t; }
    }
    __syncthreads();
    const int excl = wsum[w] + s - v;
    const int n = b * BKN + tid;
    if (n < NN) { begv[n] = b * COLCAP + excl; degv[n] = v; }
    __syncthreads();
    ncnt[tid] = excl;   // reuse as place cursors
    __syncthreads();

    // place
    if (tid < NBIN) {
        const unsigned int* cp = bstage + ((size_t)b * NBIN + tid) * SUBCAP;
        const int c = ccnt[tid];
        int* cb = col + (size_t)b * COLCAP;
        for (int j = 0; j < c; ++j) {
            unsigned wd = cp[j];
            int r = atomicAdd(&ncnt[wd >> 16], 1);
            cb[r] = (int)(wd & 0xFFFFu);
        }
    }
}

// ---------------- layer-1 CSR mean-aggregate over bf16 x --------------------
// wave per node; 16 lanes x ushort4 per edge -> 4 edges/instr, 8 in flight
__global__ __launch_bounds__(256) void k_agg1(const int* __restrict__ begv,
                                              const int* __restrict__ degv,
                                              const int* __restrict__ col,
                                              const unsigned short* __restrict__ xbu,
                                              float* __restrict__ mean) {
    const int node = blockIdx.x * 4 + (threadIdx.x >> 6);
    const int lane = threadIdx.x & 63;
    const int g = lane >> 4;        // edge group 0..3
    const int s = lane & 15;        // channels s*4 .. s*4+3
    if (node >= NN) return;
    const int beg = begv[node], dg = degv[node];
    const int end = beg + dg;
    float a0 = 0.f, a1 = 0.f, a2 = 0.f, a3 = 0.f;
    int i = beg;
    for (; i + 8 <= end; i += 8) {
        const int eA = col[i + g];
        const int eB = col[i + 4 + g];
        ushort4 ua = *(const ushort4*)(xbu + eA * CH + s * 4);
        ushort4 ub = *(const ushort4*)(xbu + eB * CH + s * 4);
        a0 += __uint_as_float((unsigned)ua.x << 16) + __uint_as_float((unsigned)ub.x << 16);
        a1 += __uint_as_float((unsigned)ua.y << 16) + __uint_as_float((unsigned)ub.y << 16);
        a2 += __uint_as_float((unsigned)ua.z << 16) + __uint_as_float((unsigned)ub.z << 16);
        a3 += __uint_as_float((unsigned)ua.w << 16) + __uint_as_float((unsigned)ub.w << 16);
    }
    for (; i < end; i += 4) {
        if (g < end - i) {
            const int e = col[i + g];
            ushort4 u = *(const ushort4*)(xbu + e * CH + s * 4);
            a0 += __uint_as_float((unsigned)u.x << 16);
            a1 += __uint_as_float((unsigned)u.y << 16);
            a2 += __uint_as_float((unsigned)u.z << 16);
            a3 += __uint_as_float((unsigned)u.w << 16);
        }
    }
    a0 += __shfl_xor(a0, 16); a0 += __shfl_xor(a0, 32);
    a1 += __shfl_xor(a1, 16); a1 += __shfl_xor(a1, 32);
    a2 += __shfl_xor(a2, 16); a2 += __shfl_xor(a2, 32);
    a3 += __shfl_xor(a3, 16); a3 += __shfl_xor(a3, 32);
    if (lane < 16) {
        const float inv = dg ? 1.0f / (float)dg : 0.0f;
        *(float4*)(mean + (size_t)node * CH + lane * 4) =
            make_float4(a0 * inv, a1 * inv, a2 * inv, a3 * inv);
    }
}

// ---------------- fused tiled GEMM: [32 nodes x 128k] @ [128k x 64] ---------
__global__ __launch_bounds__(256, 2) void k_fused(
        const float* __restrict__ x, const float* __restrict__ mean,
        const float* __restrict__ WlT, const float* __restrict__ WrT,
        const float* __restrict__ b1,
        const float* __restrict__ W2l, const float* __restrict__ W2r,
        const float* __restrict__ b2,
        float* __restrict__ hl2, float* __restrict__ out) {
    __shared__ float As[32][132];
    __shared__ float Ws[128][64];
    const int tid = threadIdx.x;
    const int n0 = blockIdx.x * 32;

    for (int idx = tid; idx < 1024; idx += 256) {
        int part = idx >> 9, rem = idx & 511, row = rem >> 4, q = rem & 15;
        int n = n0 + row;
        float4 v = make_float4(0.f, 0.f, 0.f, 0.f);
        if (n < NN) {
            const float* sp = part ? (x + (size_t)n * CH) : (mean + (size_t)n * CH);
            v = *(const float4*)(sp + q * 4);
        }
        *(float4*)&As[row][part * 64 + q * 4] = v;
    }
    for (int idx = tid; idx < 2048; idx += 256) {
        int r = idx >> 4, q = idx & 15;
        const float* wp = (r < 64) ? (WlT + r * CH) : (WrT + (r - 64) * CH);
        *(float4*)&Ws[r][q * 4] = *(const float4*)(wp + q * 4);
    }
    __syncthreads();

    const int nd0 = (tid >> 4) * 2;   // 0..30
    const int oc0 = (tid & 15) * 4;   // 0..60
    float acc[2][4] = {{0.f, 0.f, 0.f, 0.f}, {0.f, 0.f, 0.f, 0.f}};

    for (int kb = 0; kb < 32; ++kb) {
        float4 a0 = *(const float4*)&As[nd0][kb * 4];
        float4 a1 = *(const float4*)&As[nd0 + 1][kb * 4];
        float4 w0 = *(const float4*)&Ws[kb * 4 + 0][oc0];
        float4 w1 = *(const float4*)&Ws[kb * 4 + 1][oc0];
        float4 w2 = *(const float4*)&Ws[kb * 4 + 2][oc0];
        float4 w3 = *(const float4*)&Ws[kb * 4 + 3][oc0];
#pragma unroll
        for (int j = 0; j < 4; ++j) {
            const float u0 = ((const float*)&w0)[j];
            const float u1 = ((const float*)&w1)[j];
            const float u2 = ((const float*)&w2)[j];
            const float u3 = ((const float*)&w3)[j];
            acc[0][j] = fmaf(a0.x, u0, fmaf(a0.y, u1, fmaf(a0.z, u2, fmaf(a0.w, u3, acc[0][j]))));
            acc[1][j] = fmaf(a1.x, u0, fmaf(a1.y, u1, fmaf(a1.z, u2, fmaf(a1.w, u3, acc[1][j]))));
        }
    }

    float b1v[4], wl0[4], wl1[4], wr0[4], wr1[4];
#pragma unroll
    for (int j = 0; j < 4; ++j) {
        b1v[j] = b1[oc0 + j];
        wl0[j] = W2l[oc0 + j];  wl1[j] = W2l[64 + oc0 + j];
        wr0[j] = W2r[oc0 + j];  wr1[j] = W2r[64 + oc0 + j];
    }
    const float b20 = b2[0], b21 = b2[1];
#pragma unroll
    for (int nd = 0; nd < 2; ++nd) {
        float a0 = 0.f, a1 = 0.f, r0 = 0.f, r1 = 0.f;
#pragma unroll
        for (int j = 0; j < 4; ++j) {
            const float h = fmaxf(acc[nd][j] + b1v[j], 0.0f);  // relu; dropout=id
            a0 = fmaf(h, wl0[j], a0);
            a1 = fmaf(h, wl1[j], a1);
            r0 = fmaf(h, wr0[j], r0);
            r1 = fmaf(h, wr1[j], r1);
        }
#pragma unroll
        for (int off = 1; off < 16; off <<= 1) {
            a0 += __shfl_xor(a0, off);
            a1 += __shfl_xor(a1, off);
            r0 += __shfl_xor(r0, off);
            r1 += __shfl_xor(r1, off);
        }
        const int n = n0 + nd0 + nd;
        if ((tid & 15) == 0 && n < NN) {
            *(float2*)(hl2 + (size_t)n * 2) = make_float2(a0, a1);
            *(float2*)(out + (size_t)n * 2) = make_float2(b20 + r0, b21 + r1);
        }
    }
}

// ---------------- layer-2 CSR mean-aggregate + add into out -----------------
__global__ __launch_bounds__(256) void k_agg2(const int* __restrict__ begv,
                                              const int* __restrict__ degv,
                                              const int* __restrict__ col,
                                              const float2* __restrict__ hl2,
                                              float2* __restrict__ out) {
    int t = blockIdx.x * 256 + threadIdx.x;
    int node = t >> 3;
    int sl = t & 7;
    if (node >= NN) return;
    const int beg = begv[node], dg = degv[node];
    const int end = beg + dg;
    float ax = 0.0f, ay = 0.0f;
    for (int i = beg + sl; i < end; i += 8) {
        float2 v = hl2[col[i]];
        ax += v.x; ay += v.y;
    }
#pragma unroll
    for (int off = 4; off > 0; off >>= 1) {
        ax += __shfl_xor(ax, off);
        ay += __shfl_xor(ay, off);
    }
    if (sl == 0) {
        const float inv = dg ? 1.0f / (float)dg : 0.0f;
        float2 o = out[node];
        o.x += ax * inv;
        o.y += ay * inv;
        out[node] = o;
    }
}

extern "C" void kernel_launch(void* const* d_in, const int* in_sizes, int n_in,
                              void* d_out, int out_size, void* d_ws, size_t ws_size,
                              hipStream_t stream) {
    const float* x   = (const float*)d_in[0];
    const int*   ei  = (const int*)d_in[1];
    const float* W1l = (const float*)d_in[2];
    const float* W1r = (const float*)d_in[3];
    const float* b1  = (const float*)d_in[4];
    const float* W2l = (const float*)d_in[5];
    const float* W2r = (const float*)d_in[6];
    const float* b2  = (const float*)d_in[7];
    float* out = (float*)d_out;

    const int* src = ei;        // edge_index[0, :]
    const int* dst = ei + NE;   // edge_index[1, :]

    // workspace layout (~34 MiB; every consumed byte rewritten each call)
    char* wsp = (char*)d_ws;
    int*          lcnt   = (int*)wsp;                              // NBIN*NBKT
    int*          begv   = lcnt + NBIN * NBKT;                     // NN (pad)
    int*          degv   = begv + 50048;                           // NN (pad)
    unsigned int* bstage = (unsigned int*)(degv + 50048);          // NBKT*NBIN*SUBCAP
    int*          col    = (int*)(bstage + (size_t)NBKT * NBIN * SUBCAP); // NBKT*COLCAP
    float*        mean   = (float*)(col + (size_t)NBKT * COLCAP);  // NN*CH
    float*        hl2    = mean + (size_t)NN * CH;                 // NN*2
    __hip_bfloat16* xbf  = (__hip_bfloat16*)(hl2 + (size_t)NN * 2);// NN*CH bf16
    float*        WlT    = (float*)(xbf + (size_t)NN * CH);        // 4096
    float*        WrT    = WlT + CH * CH;                          // 4096

    k_prep<<<NCVT + NBIN, 256, 0, stream>>>(x, xbf, W1l, W1r, WlT, WrT,
                                            src, dst, lcnt, bstage);
    k_sort<<<NBKT, 256, 0, stream>>>(bstage, lcnt, begv, degv, col);
    k_agg1<<<(NN + 3) / 4, 256, 0, stream>>>(begv, degv, col,
                                             (const unsigned short*)xbf, mean);
    k_fused<<<(NN + 31) / 32, 256, 0, stream>>>(
        x, mean, WlT, WrT, b1, W2l, W2r, b2, hl2, out);
    k_agg2<<<(8 * NN + 255) / 256, 256, 0, stream>>>(
        begv, degv, col, (const float2*)hl2, (float2*)out);
}